// Round 1
// baseline (551.835 us; speedup 1.0000x reference)
//
#include <hip/hip_runtime.h>
#include <math.h>

#define Bz 4
#define Lz 1500
#define Dz 512
#define NHz 8
#define Nz (Bz*Lz)
#define PEPSf 1.1920929e-07f

// ---------------- row prep: U = l2norm(hidden) ; HN = layernorm(hidden) ----------------
__global__ __launch_bounds__(256) void k_rowprep(const float* __restrict__ h,
    const float* __restrict__ g, const float* __restrict__ bb,
    float* __restrict__ U, float* __restrict__ HN) {
  const int row = blockIdx.x;
  const int t = threadIdx.x;
  const float* x = h + (size_t)row * Dz;
  float x0 = x[t], x1 = x[t + 256];
  float s = x0 + x1, q = x0 * x0 + x1 * x1;
  #pragma unroll
  for (int o = 32; o > 0; o >>= 1) { s += __shfl_xor(s, o, 64); q += __shfl_xor(q, o, 64); }
  __shared__ float ls[4], lq[4];
  if ((t & 63) == 0) { ls[t >> 6] = s; lq[t >> 6] = q; }
  __syncthreads();
  s = ls[0] + ls[1] + ls[2] + ls[3];
  q = lq[0] + lq[1] + lq[2] + lq[3];
  float un = 1.f / fmaxf(sqrtf(q), 1e-8f);
  float* up = U + (size_t)row * Dz;
  up[t] = x0 * un; up[t + 256] = x1 * un;
  float mu = s * (1.f / 512.f);
  float var = fmaxf(q * (1.f / 512.f) - mu * mu, 0.f);
  float r = rsqrtf(var + 1e-5f);
  float* hp = HN + (size_t)row * Dz;
  hp[t]       = (x0 - mu) * r * g[t]       + bb[t];
  hp[t + 256] = (x1 - mu) * r * g[t + 256] + bb[t + 256];
}

// ---------------- V = l2norm(M) in place ----------------
__global__ __launch_bounds__(256) void k_rownorm(float* __restrict__ M) {
  const int row = blockIdx.x;
  const int t = threadIdx.x;
  float* x = M + (size_t)row * Dz;
  float x0 = x[t], x1 = x[t + 256];
  float q = x0 * x0 + x1 * x1;
  #pragma unroll
  for (int o = 32; o > 0; o >>= 1) q += __shfl_xor(q, o, 64);
  __shared__ float lq[4];
  if ((t & 63) == 0) lq[t >> 6] = q;
  __syncthreads();
  q = lq[0] + lq[1] + lq[2] + lq[3];
  float un = 1.f / fmaxf(sqrtf(q), 1e-8f);
  x[t] = x0 * un; x[t + 256] = x1 * un;
}

// ---------------- NT GEMM: out[n,m] = epi( sum_k A[n,k]*W[m,k] ) ----------------
// 128x64 tile, 256 threads, 8x4 microtile, BK=16, fp32.
__global__ __launch_bounds__(256) void gemm_nt(const float* __restrict__ A,
    const float* __restrict__ W, const float* __restrict__ bias,
    const float* __restrict__ addsrc, float* __restrict__ out,
    int N, int doGelu) {
  __shared__ float As[16][132];  // padded: float4-aligned rows (132*4=528=33*16)
  __shared__ float Bs[16][68];
  const int t = threadIdx.x;
  const int row0 = blockIdx.y * 128, col0 = blockIdx.x * 64;
  const int lr = t >> 2;          // 0..63
  const int lk = (t & 3) << 2;    // 0,4,8,12
  const int tn = t & 15, tm = t >> 4;
  float acc[8][4] = {};
  const bool v0 = (row0 + lr) < N, v1 = (row0 + lr + 64) < N;
  const float* Ar0 = A + (size_t)(row0 + lr) * 512 + lk;
  const float* Ar1 = A + (size_t)(row0 + lr + 64) * 512 + lk;
  const float* Wr  = W + (size_t)(col0 + lr) * 512 + lk;
  for (int k0 = 0; k0 < 512; k0 += 16) {
    float4 a0 = v0 ? *(const float4*)(Ar0 + k0) : make_float4(0.f, 0.f, 0.f, 0.f);
    float4 a1 = v1 ? *(const float4*)(Ar1 + k0) : make_float4(0.f, 0.f, 0.f, 0.f);
    float4 bw = *(const float4*)(Wr + k0);
    __syncthreads();
    As[lk + 0][lr] = a0.x; As[lk + 1][lr] = a0.y; As[lk + 2][lr] = a0.z; As[lk + 3][lr] = a0.w;
    As[lk + 0][lr + 64] = a1.x; As[lk + 1][lr + 64] = a1.y; As[lk + 2][lr + 64] = a1.z; As[lk + 3][lr + 64] = a1.w;
    Bs[lk + 0][lr] = bw.x; Bs[lk + 1][lr] = bw.y; Bs[lk + 2][lr] = bw.z; Bs[lk + 3][lr] = bw.w;
    __syncthreads();
    #pragma unroll
    for (int k = 0; k < 16; ++k) {
      const float4 af0 = *(const float4*)&As[k][tn * 8];
      const float4 af1 = *(const float4*)&As[k][tn * 8 + 4];
      const float4 bf  = *(const float4*)&Bs[k][tm * 4];
      float a[8] = {af0.x, af0.y, af0.z, af0.w, af1.x, af1.y, af1.z, af1.w};
      float bv[4] = {bf.x, bf.y, bf.z, bf.w};
      #pragma unroll
      for (int i = 0; i < 8; ++i)
        #pragma unroll
        for (int j = 0; j < 4; ++j)
          acc[i][j] += a[i] * bv[j];
    }
  }
  const int c0 = col0 + tm * 4;
  #pragma unroll
  for (int i = 0; i < 8; ++i) {
    int r = row0 + tn * 8 + i;
    if (r >= N) break;
    float vv[4];
    #pragma unroll
    for (int j = 0; j < 4; ++j) {
      float v = acc[i][j];
      if (bias)   v += bias[c0 + j];
      if (addsrc) v += addsrc[(size_t)r * 512 + c0 + j];
      if (doGelu) v = 0.5f * v * (1.f + erff(v * 0.70710678118654752f));
      vv[j] = v;
    }
    *(float4*)(out + (size_t)r * 512 + c0) = make_float4(vv[0], vv[1], vv[2], vv[3]);
  }
}

// ---------------- cos -> probs (padded). probs[b,L-1]=0 ----------------
__global__ void k_probs(const float* __restrict__ QF, const float* __restrict__ KF,
                        const float* __restrict__ simb, float* __restrict__ probs) {
  const int l = blockIdx.x, b = blockIdx.y, t = threadIdx.x;  // 64 threads
  if (l == Lz - 1) { if (t == 0) probs[(size_t)b * Lz + l] = 0.f; return; }
  const float* qp = QF + ((size_t)b * Lz + l) * Dz;
  const float* kp = KF + ((size_t)b * Lz + l + 1) * Dz;
  float acc = 0.f;
  for (int i = t; i < Dz; i += 64) acc += qp[i] * kp[i];
  #pragma unroll
  for (int o = 32; o > 0; o >>= 1) acc += __shfl_xor(acc, o, 64);
  if (t == 0) {
    float p = (1.f - (acc + simb[0])) * 0.5f;
    probs[(size_t)b * Lz + l] = fminf(fmaxf(p, 0.f), 1.f);
  }
}

// ---------------- boundaries, emergency, exclusive-scan segments ----------------
__global__ __launch_bounds__(256) void k_boundary(const float* __restrict__ probs,
    const float* __restrict__ un, const float* __restrict__ lengths,
    int* __restrict__ seg_start, int* __restrict__ seg_meta) {
  const int b = blockIdx.x, t = threadIdx.x;
  __shared__ float hard[Lz];
  __shared__ float ps[256];
  __shared__ float ws4[4];
  const float len = lengths[b];
  const int valid_len = min((int)(len * (Lz + 1)) - 1, Lz);
  const int Lm = (int)(len * Lz);
  const bool trunc = valid_len < Lz;
  for (int l = t; l < Lz; l += 256) {
    float p = probs[(size_t)b * Lz + l];
    p = fminf(fmaxf(p, PEPSf), 1.f - PEPSf);
    float u = un[(size_t)b * Lz + l];
    u = fminf(fmaxf(u, PEPSf), 1.f - PEPSf);
    float z = logf(p) - log1pf(-p) + logf(u) - log1pf(-u);
    float soft = 1.f / (1.f + expf(-z));
    float hd = soft > 0.5f ? 1.f : 0.f;
    if (trunc && l >= valid_len) hd = (l == valid_len) ? 1.f : 0.f;
    hard[l] = hd;
  }
  __syncthreads();
  float sm = 0.f;
  for (int l = t; l < Lz; l += 256) sm += hard[l];
  #pragma unroll
  for (int o = 32; o > 0; o >>= 1) sm += __shfl_xor(sm, o, 64);
  if ((t & 63) == 0) ws4[t >> 6] = sm;
  __syncthreads();
  float total = ws4[0] + ws4[1] + ws4[2] + ws4[3];
  if (total == 0.f && t == 0) hard[min(valid_len, Lz - 1)] = 1.f;
  __syncthreads();
  // per-thread chunk of 6, then Hillis-Steele over partials
  const int l0 = t * 6;
  float loc = 0.f;
  for (int i = 0; i < 6; ++i) { int l = l0 + i; if (l < Lz) loc += hard[l]; }
  ps[t] = loc;
  __syncthreads();
  for (int off = 1; off < 256; off <<= 1) {
    float v = (t >= off) ? ps[t - off] : 0.f;
    __syncthreads();
    ps[t] += v;
    __syncthreads();
  }
  float run = ps[t] - loc;  // exclusive prefix at l0
  for (int i = 0; i < 6; ++i) {
    int l = l0 + i; if (l >= Lz) break;
    int seg = (int)(run + 0.5f);
    if (l == 0) seg_start[b * (Lz + 1) + 0] = 0;
    else if (hard[l - 1] > 0.5f) seg_start[b * (Lz + 1) + seg] = l;
    if (l == Lz - 1) {
      int nseg = seg + 1;
      seg_meta[b * 2 + 0] = nseg;
      seg_meta[b * 2 + 1] = Lm;
      seg_start[b * (Lz + 1) + nseg] = Lz;
    }
    run += hard[l];
  }
}

// ---------------- wq_eff[h,d] = sum_e lq[h*64+e] * Wpk[h*64+e, d] ----------------
__global__ void k_wqeff(const float* __restrict__ lq, const float* __restrict__ Wpk,
                        float* __restrict__ wqe) {
  const int h = blockIdx.x, d = threadIdx.x;  // 512 threads
  float acc = 0.f;
  for (int e = 0; e < 64; ++e) acc += lq[h * 64 + e] * Wpk[(size_t)(h * 64 + e) * Dz + d];
  wqe[h * Dz + d] = acc;
}

// ---------------- base[row,h] = 0.125 * dot(HN[row], wq_eff[h]) ----------------
__global__ __launch_bounds__(256) void k_base(const float* __restrict__ HN,
    const float* __restrict__ wqe, float* __restrict__ base) {
  const int row = blockIdx.x, t = threadIdx.x;
  __shared__ float xs[Dz];
  xs[t] = HN[(size_t)row * Dz + t];
  xs[t + 256] = HN[(size_t)row * Dz + t + 256];
  __syncthreads();
  const int h = t >> 5, lane = t & 31;
  float acc = 0.f;
  for (int d = lane; d < Dz; d += 32) acc += xs[d] * wqe[h * Dz + d];
  #pragma unroll
  for (int o = 16; o > 0; o >>= 1) acc += __shfl_xor(acc, o, 32);
  if (lane == 0) base[(size_t)row * NHz + h] = acc * 0.125f;
}

// ---------------- segment softmax-pool over vals ----------------
__global__ __launch_bounds__(256) void k_pool(const float* __restrict__ base,
    const float* __restrict__ VALS, const int* __restrict__ seg_start,
    const int* __restrict__ seg_meta, float* __restrict__ POOLED) {
  const int s = blockIdx.x, b = blockIdx.y, t = threadIdx.x;
  float* out = POOLED + ((size_t)b * Lz + s) * Dz;
  const int nseg = seg_meta[b * 2], Lm = seg_meta[b * 2 + 1];
  int start = 0, end = 0;
  bool empty = true;
  if (s < nseg) {
    start = seg_start[b * (Lz + 1) + s];
    end = min(seg_start[b * (Lz + 1) + s + 1], Lm);
    empty = start >= end;
  }
  if (empty) { out[t] = 0.f; out[t + 256] = 0.f; return; }
  const int h = t >> 5, lane = t & 31;
  const float* bp = base + (size_t)b * Lz * NHz + h;
  float m = -1e30f;
  for (int l = start + lane; l < end; l += 32) m = fmaxf(m, bp[(size_t)l * NHz]);
  #pragma unroll
  for (int o = 16; o > 0; o >>= 1) m = fmaxf(m, __shfl_xor(m, o, 32));
  float den = 0.f;
  for (int l = start + lane; l < end; l += 32) den += expf(bp[(size_t)l * NHz] - m);
  #pragma unroll
  for (int o = 16; o > 0; o >>= 1) den += __shfl_xor(den, o, 32);
  float a0 = 0.f, a1 = 0.f;
  const float* vp = VALS + (size_t)b * Lz * Dz + h * 64 + lane;
  for (int l = start; l < end; ++l) {
    float w = expf(bp[(size_t)l * NHz] - m);
    a0 += w * vp[(size_t)l * Dz];
    a1 += w * vp[(size_t)l * Dz + 32];
  }
  float inv = 1.f / den;
  out[h * 64 + lane] = a0 * inv;
  out[h * 64 + lane + 32] = a1 * inv;
}

extern "C" void kernel_launch(void* const* d_in, const int* in_sizes, int n_in,
                              void* d_out, int out_size, void* d_ws, size_t ws_size,
                              hipStream_t stream) {
  const float* hidden  = (const float*)d_in[0];
  const float* lengths = (const float*)d_in[1];
  const float* unoise  = (const float*)d_in[2];
  const float* W1  = (const float*)d_in[3];
  const float* b1  = (const float*)d_in[4];
  const float* W2  = (const float*)d_in[5];
  const float* b2  = (const float*)d_in[6];
  const float* Wq  = (const float*)d_in[7];
  const float* Wk  = (const float*)d_in[8];
  const float* simb   = (const float*)d_in[9];
  const float* lquery = (const float*)d_in[10];
  const float* Wpk = (const float*)d_in[11];
  const float* Wpv = (const float*)d_in[12];
  const float* Wpo = (const float*)d_in[13];
  const float* lng = (const float*)d_in[14];
  const float* lnb = (const float*)d_in[15];
  float* out = (float*)d_out;

  char* ws = (char*)d_ws;
  const size_t S = (size_t)Nz * Dz * 4;   // 12,288,000 B per slot
  float* U  = (float*)(ws);               // U -> KF
  float* HN = (float*)(ws + S);           // HN (persistent)
  float* C  = (float*)(ws + 2 * S);       // T1 -> QF -> POOLED
  float* Dv = (float*)(ws + 3 * S);       // M/V -> VALS
  char* tail = ws + 4 * S;
  float* probs  = (float*)tail; tail += 24064;   // B*L floats
  float* base   = (float*)tail; tail += 192000;  // B*L*NH floats
  int* segst    = (int*)tail;   tail += 24064;   // B*(L+1) ints
  int* segmeta  = (int*)tail;   tail += 256;     // B*2 ints
  float* wqe    = (float*)tail;                  // NH*D floats

  dim3 gg(Dz / 64, (Nz + 127) / 128);

  k_rowprep<<<Nz, 256, 0, stream>>>(hidden, lng, lnb, U, HN);
  gemm_nt<<<gg, 256, 0, stream>>>(U, W1, b1, nullptr, C, Nz, 1);        // T1 = gelu(U@W1^T+b1)
  gemm_nt<<<gg, 256, 0, stream>>>(C, W2, b2, U, Dv, Nz, 0);             // M = T1@W2^T+b2+U
  k_rownorm<<<Nz, 256, 0, stream>>>(Dv);                                 // V = l2norm(M)
  gemm_nt<<<gg, 256, 0, stream>>>(Dv, Wq, nullptr, nullptr, C, Nz, 0);   // QF
  gemm_nt<<<gg, 256, 0, stream>>>(Dv, Wk, nullptr, nullptr, U, Nz, 0);   // KF
  k_probs<<<dim3(Lz, Bz), 64, 0, stream>>>(C, U, simb, probs);
  k_boundary<<<Bz, 256, 0, stream>>>(probs, unoise, lengths, segst, segmeta);
  gemm_nt<<<gg, 256, 0, stream>>>(HN, Wpv, nullptr, nullptr, Dv, Nz, 0); // VALS
  k_wqeff<<<NHz, 512, 0, stream>>>(lquery, Wpk, wqe);
  k_base<<<Nz, 256, 0, stream>>>(HN, wqe, base);
  k_pool<<<dim3(Lz, Bz), 256, 0, stream>>>(base, Dv, segst, segmeta, C); // POOLED
  gemm_nt<<<gg, 256, 0, stream>>>(C, Wpo, nullptr, nullptr, out, Nz, 0); // out = POOLED@Wpo^T
}

// Round 2
// 512.442 us; speedup vs baseline: 1.0769x; 1.0769x over previous
//
#include <hip/hip_runtime.h>
#include <math.h>

#define Bz 4
#define Lz 1500
#define Dz 512
#define NHz 8
#define Nz (Bz*Lz)
#define PEPSf 1.1920929e-07f

typedef __bf16 bf16x8 __attribute__((ext_vector_type(8)));
typedef unsigned short u16x8 __attribute__((ext_vector_type(8)));
typedef float f32x4 __attribute__((ext_vector_type(4)));

// ---------------- row prep: U = l2norm(hidden) ; HN = layernorm(hidden) ----------------
__global__ __launch_bounds__(256) void k_rowprep(const float* __restrict__ h,
    const float* __restrict__ g, const float* __restrict__ bb,
    float* __restrict__ U, float* __restrict__ HN) {
  const int row = blockIdx.x;
  const int t = threadIdx.x;
  const float* x = h + (size_t)row * Dz;
  float x0 = x[t], x1 = x[t + 256];
  float s = x0 + x1, q = x0 * x0 + x1 * x1;
  #pragma unroll
  for (int o = 32; o > 0; o >>= 1) { s += __shfl_xor(s, o, 64); q += __shfl_xor(q, o, 64); }
  __shared__ float ls[4], lq[4];
  if ((t & 63) == 0) { ls[t >> 6] = s; lq[t >> 6] = q; }
  __syncthreads();
  s = ls[0] + ls[1] + ls[2] + ls[3];
  q = lq[0] + lq[1] + lq[2] + lq[3];
  float un = 1.f / fmaxf(sqrtf(q), 1e-8f);
  float* up = U + (size_t)row * Dz;
  up[t] = x0 * un; up[t + 256] = x1 * un;
  float mu = s * (1.f / 512.f);
  float var = fmaxf(q * (1.f / 512.f) - mu * mu, 0.f);
  float r = rsqrtf(var + 1e-5f);
  float* hp = HN + (size_t)row * Dz;
  hp[t]       = (x0 - mu) * r * g[t]       + bb[t];
  hp[t + 256] = (x1 - mu) * r * g[t + 256] + bb[t + 256];
}

// ---------------- V = l2norm(M) in place ----------------
__global__ __launch_bounds__(256) void k_rownorm(float* __restrict__ M) {
  const int row = blockIdx.x;
  const int t = threadIdx.x;
  float* x = M + (size_t)row * Dz;
  float x0 = x[t], x1 = x[t + 256];
  float q = x0 * x0 + x1 * x1;
  #pragma unroll
  for (int o = 32; o > 0; o >>= 1) q += __shfl_xor(q, o, 64);
  __shared__ float lq[4];
  if ((t & 63) == 0) lq[t >> 6] = q;
  __syncthreads();
  q = lq[0] + lq[1] + lq[2] + lq[3];
  float un = 1.f / fmaxf(sqrtf(q), 1e-8f);
  x[t] = x0 * un; x[t + 256] = x1 * un;
}

// ---------------- fp32 -> bf16 RNE helpers ----------------
__device__ __forceinline__ unsigned short f2bf(float f) {
  unsigned u = __float_as_uint(f);
  return (unsigned short)((u + 0x7fffu + ((u >> 16) & 1u)) >> 16);
}
__device__ __forceinline__ float bf2f(unsigned short b) {
  return __uint_as_float(((unsigned)b) << 16);
}

// ---------------- MFMA NT GEMM: out[n,m] = epi( sum_k A[n,k]*W[m,k] ) ----------------
// 128x128 block tile, 4 waves (each 64x64), 16x16x32 bf16 MFMA.
// SPLIT==3: bf16x3 (Ah*Bh + Ah*Bl + Al*Bh) near-fp32 accuracy.
// SPLIT==1: plain bf16 (hi only).
template<int SPLIT>
__global__ __launch_bounds__(256) void gemm_mf(const float* __restrict__ A,
    const float* __restrict__ W, const float* __restrict__ bias,
    const float* __restrict__ addsrc, float* __restrict__ out,
    int N, int doGelu) {
  extern __shared__ unsigned short smem[];
  unsigned short* sAh = smem;            // [128][32]
  unsigned short* sBh = smem + 4096;     // [128][32]
  unsigned short* sAl = smem + 8192;     // SPLIT==3 only
  unsigned short* sBl = smem + 12288;

  const int t = threadIdx.x;
  const int row0 = blockIdx.y * 128, col0 = blockIdx.x * 128;

  // staging coords: each thread owns 4 units of 8 fp32 (2 A-units, 2 B-units)
  const int ar = t >> 2;            // 0..63
  const int ak = (t & 3) << 3;      // 0,8,16,24
  const bool va0 = (row0 + ar) < N, va1 = (row0 + ar + 64) < N;
  const float* Ap0 = A + (size_t)(row0 + ar) * 512 + ak;
  const float* Ap1 = A + (size_t)(row0 + ar + 64) * 512 + ak;
  const float* Wp0 = W + (size_t)(col0 + ar) * 512 + ak;
  const float* Wp1 = W + (size_t)(col0 + ar + 64) * 512 + ak;

  // MFMA coords
  const int w = t >> 6, l = t & 63;
  const int wr = (w & 1) * 64, wc = (w >> 1) * 64;
  const int fm = l & 15, fq = l >> 4;
  int aoff[4], boff[4];
  #pragma unroll
  for (int i = 0; i < 4; ++i) {
    aoff[i] = (wr + i * 16 + fm) * 32 + fq * 8;
    boff[i] = (wc + i * 16 + fm) * 32 + fq * 8;
  }

  f32x4 acc[4][4];
  #pragma unroll
  for (int i = 0; i < 4; ++i)
    #pragma unroll
    for (int j = 0; j < 4; ++j)
      acc[i][j] = (f32x4){0.f, 0.f, 0.f, 0.f};

  const float4 z4 = make_float4(0.f, 0.f, 0.f, 0.f);

  for (int k0 = 0; k0 < 512; k0 += 32) {
    float4 pa0 = va0 ? *(const float4*)(Ap0 + k0) : z4;
    float4 qa0 = va0 ? *(const float4*)(Ap0 + k0 + 4) : z4;
    float4 pa1 = va1 ? *(const float4*)(Ap1 + k0) : z4;
    float4 qa1 = va1 ? *(const float4*)(Ap1 + k0 + 4) : z4;
    float4 pb0 = *(const float4*)(Wp0 + k0);
    float4 qb0 = *(const float4*)(Wp0 + k0 + 4);
    float4 pb1 = *(const float4*)(Wp1 + k0);
    float4 qb1 = *(const float4*)(Wp1 + k0 + 4);
    __syncthreads();   // previous stage's LDS reads complete
    {
      float xs[4][8] = {
        {pa0.x, pa0.y, pa0.z, pa0.w, qa0.x, qa0.y, qa0.z, qa0.w},
        {pa1.x, pa1.y, pa1.z, pa1.w, qa1.x, qa1.y, qa1.z, qa1.w},
        {pb0.x, pb0.y, pb0.z, pb0.w, qb0.x, qb0.y, qb0.z, qb0.w},
        {pb1.x, pb1.y, pb1.z, pb1.w, qb1.x, qb1.y, qb1.z, qb1.w}};
      unsigned short* dh[4] = {sAh + ar * 32 + ak, sAh + (ar + 64) * 32 + ak,
                               sBh + ar * 32 + ak, sBh + (ar + 64) * 32 + ak};
      #pragma unroll
      for (int uidx = 0; uidx < 4; ++uidx) {
        u16x8 h, lo;
        #pragma unroll
        for (int j = 0; j < 8; ++j) {
          unsigned short hb = f2bf(xs[uidx][j]);
          h[j] = hb;
          if (SPLIT == 3) lo[j] = f2bf(xs[uidx][j] - bf2f(hb));
        }
        *(u16x8*)dh[uidx] = h;
        if (SPLIT == 3) *(u16x8*)(dh[uidx] + 8192) = lo;  // sAl/sBl mirror at +8192
      }
    }
    __syncthreads();
    bf16x8 ah[4], bh[4];
    #pragma unroll
    for (int i = 0; i < 4; ++i) {
      ah[i] = __builtin_bit_cast(bf16x8, *(const u16x8*)(sAh + aoff[i]));
      bh[i] = __builtin_bit_cast(bf16x8, *(const u16x8*)(sBh + boff[i]));
    }
    if (SPLIT == 3) {
      bf16x8 al[4], bl[4];
      #pragma unroll
      for (int i = 0; i < 4; ++i) {
        al[i] = __builtin_bit_cast(bf16x8, *(const u16x8*)(sAl + aoff[i]));
        bl[i] = __builtin_bit_cast(bf16x8, *(const u16x8*)(sBl + boff[i]));
      }
      #pragma unroll
      for (int i = 0; i < 4; ++i)
        #pragma unroll
        for (int j = 0; j < 4; ++j) {
          acc[i][j] = __builtin_amdgcn_mfma_f32_16x16x32_bf16(ah[i], bh[j], acc[i][j], 0, 0, 0);
          acc[i][j] = __builtin_amdgcn_mfma_f32_16x16x32_bf16(ah[i], bl[j], acc[i][j], 0, 0, 0);
          acc[i][j] = __builtin_amdgcn_mfma_f32_16x16x32_bf16(al[i], bh[j], acc[i][j], 0, 0, 0);
        }
    } else {
      #pragma unroll
      for (int i = 0; i < 4; ++i)
        #pragma unroll
        for (int j = 0; j < 4; ++j)
          acc[i][j] = __builtin_amdgcn_mfma_f32_16x16x32_bf16(ah[i], bh[j], acc[i][j], 0, 0, 0);
    }
  }

  // epilogue: C/D layout col = l&15, row = (l>>4)*4 + reg
  #pragma unroll
  for (int i = 0; i < 4; ++i) {
    #pragma unroll
    for (int r = 0; r < 4; ++r) {
      const int grow = row0 + wr + i * 16 + fq * 4 + r;
      if (grow >= N) continue;
      #pragma unroll
      for (int j = 0; j < 4; ++j) {
        const int gcol = col0 + wc + j * 16 + fm;
        float v = acc[i][j][r];
        if (bias)   v += bias[gcol];
        if (addsrc) v += addsrc[(size_t)grow * 512 + gcol];
        if (doGelu) v = 0.5f * v * (1.f + erff(v * 0.70710678118654752f));
        out[(size_t)grow * 512 + gcol] = v;
      }
    }
  }
}

// ---------------- cos -> probs (padded). probs[b,L-1]=0 ----------------
__global__ void k_probs(const float* __restrict__ QF, const float* __restrict__ KF,
                        const float* __restrict__ simb, float* __restrict__ probs) {
  const int l = blockIdx.x, b = blockIdx.y, t = threadIdx.x;  // 64 threads
  if (l == Lz - 1) { if (t == 0) probs[(size_t)b * Lz + l] = 0.f; return; }
  const float* qp = QF + ((size_t)b * Lz + l) * Dz;
  const float* kp = KF + ((size_t)b * Lz + l + 1) * Dz;
  float acc = 0.f;
  for (int i = t; i < Dz; i += 64) acc += qp[i] * kp[i];
  #pragma unroll
  for (int o = 32; o > 0; o >>= 1) acc += __shfl_xor(acc, o, 64);
  if (t == 0) {
    float p = (1.f - (acc + simb[0])) * 0.5f;
    probs[(size_t)b * Lz + l] = fminf(fmaxf(p, 0.f), 1.f);
  }
}

// ---------------- boundaries, emergency, exclusive-scan segments ----------------
__global__ __launch_bounds__(256) void k_boundary(const float* __restrict__ probs,
    const float* __restrict__ un, const float* __restrict__ lengths,
    int* __restrict__ seg_start, int* __restrict__ seg_meta) {
  const int b = blockIdx.x, t = threadIdx.x;
  __shared__ float hard[Lz];
  __shared__ float ps[256];
  __shared__ float ws4[4];
  const float len = lengths[b];
  const int valid_len = min((int)(len * (Lz + 1)) - 1, Lz);
  const int Lm = (int)(len * Lz);
  const bool trunc = valid_len < Lz;
  for (int l = t; l < Lz; l += 256) {
    float p = probs[(size_t)b * Lz + l];
    p = fminf(fmaxf(p, PEPSf), 1.f - PEPSf);
    float u = un[(size_t)b * Lz + l];
    u = fminf(fmaxf(u, PEPSf), 1.f - PEPSf);
    float z = logf(p) - log1pf(-p) + logf(u) - log1pf(-u);
    float soft = 1.f / (1.f + expf(-z));
    float hd = soft > 0.5f ? 1.f : 0.f;
    if (trunc && l >= valid_len) hd = (l == valid_len) ? 1.f : 0.f;
    hard[l] = hd;
  }
  __syncthreads();
  float sm = 0.f;
  for (int l = t; l < Lz; l += 256) sm += hard[l];
  #pragma unroll
  for (int o = 32; o > 0; o >>= 1) sm += __shfl_xor(sm, o, 64);
  if ((t & 63) == 0) ws4[t >> 6] = sm;
  __syncthreads();
  float total = ws4[0] + ws4[1] + ws4[2] + ws4[3];
  if (total == 0.f && t == 0) hard[min(valid_len, Lz - 1)] = 1.f;
  __syncthreads();
  const int l0 = t * 6;
  float loc = 0.f;
  for (int i = 0; i < 6; ++i) { int l = l0 + i; if (l < Lz) loc += hard[l]; }
  ps[t] = loc;
  __syncthreads();
  for (int off = 1; off < 256; off <<= 1) {
    float v = (t >= off) ? ps[t - off] : 0.f;
    __syncthreads();
    ps[t] += v;
    __syncthreads();
  }
  float run = ps[t] - loc;
  for (int i = 0; i < 6; ++i) {
    int l = l0 + i; if (l >= Lz) break;
    int seg = (int)(run + 0.5f);
    if (l == 0) seg_start[b * (Lz + 1) + 0] = 0;
    else if (hard[l - 1] > 0.5f) seg_start[b * (Lz + 1) + seg] = l;
    if (l == Lz - 1) {
      int nseg = seg + 1;
      seg_meta[b * 2 + 0] = nseg;
      seg_meta[b * 2 + 1] = Lm;
      seg_start[b * (Lz + 1) + nseg] = Lz;
    }
    run += hard[l];
  }
}

// ---------------- wq_eff[h,d] = sum_e lq[h*64+e] * Wpk[h*64+e, d] ----------------
__global__ void k_wqeff(const float* __restrict__ lq, const float* __restrict__ Wpk,
                        float* __restrict__ wqe) {
  const int h = blockIdx.x, d = threadIdx.x;  // 512 threads
  float acc = 0.f;
  for (int e = 0; e < 64; ++e) acc += lq[h * 64 + e] * Wpk[(size_t)(h * 64 + e) * Dz + d];
  wqe[h * Dz + d] = acc;
}

// ---------------- base[row,h] = 0.125 * dot(HN[row], wq_eff[h]) ----------------
__global__ __launch_bounds__(256) void k_base(const float* __restrict__ HN,
    const float* __restrict__ wqe, float* __restrict__ base) {
  const int row = blockIdx.x, t = threadIdx.x;
  __shared__ float xs[Dz];
  xs[t] = HN[(size_t)row * Dz + t];
  xs[t + 256] = HN[(size_t)row * Dz + t + 256];
  __syncthreads();
  const int h = t >> 5, lane = t & 31;
  float acc = 0.f;
  for (int d = lane; d < Dz; d += 32) acc += xs[d] * wqe[h * Dz + d];
  #pragma unroll
  for (int o = 16; o > 0; o >>= 1) acc += __shfl_xor(acc, o, 32);
  if (lane == 0) base[(size_t)row * NHz + h] = acc * 0.125f;
}

// ---------------- segment softmax-pool over vals ----------------
__global__ __launch_bounds__(256) void k_pool(const float* __restrict__ base,
    const float* __restrict__ VALS, const int* __restrict__ seg_start,
    const int* __restrict__ seg_meta, float* __restrict__ POOLED) {
  const int s = blockIdx.x, b = blockIdx.y, t = threadIdx.x;
  float* out = POOLED + ((size_t)b * Lz + s) * Dz;
  const int nseg = seg_meta[b * 2], Lm = seg_meta[b * 2 + 1];
  int start = 0, end = 0;
  bool empty = true;
  if (s < nseg) {
    start = seg_start[b * (Lz + 1) + s];
    end = min(seg_start[b * (Lz + 1) + s + 1], Lm);
    empty = start >= end;
  }
  if (empty) { out[t] = 0.f; out[t + 256] = 0.f; return; }
  const int h = t >> 5, lane = t & 31;
  const float* bp = base + (size_t)b * Lz * NHz + h;
  float m = -1e30f;
  for (int l = start + lane; l < end; l += 32) m = fmaxf(m, bp[(size_t)l * NHz]);
  #pragma unroll
  for (int o = 16; o > 0; o >>= 1) m = fmaxf(m, __shfl_xor(m, o, 32));
  float den = 0.f;
  for (int l = start + lane; l < end; l += 32) den += expf(bp[(size_t)l * NHz] - m);
  #pragma unroll
  for (int o = 16; o > 0; o >>= 1) den += __shfl_xor(den, o, 32);
  float a0 = 0.f, a1 = 0.f;
  const float* vp = VALS + (size_t)b * Lz * Dz + h * 64 + lane;
  for (int l = start; l < end; ++l) {
    float w = expf(bp[(size_t)l * NHz] - m);
    a0 += w * vp[(size_t)l * Dz];
    a1 += w * vp[(size_t)l * Dz + 32];
  }
  float inv = 1.f / den;
  out[h * 64 + lane] = a0 * inv;
  out[h * 64 + lane + 32] = a1 * inv;
}

extern "C" void kernel_launch(void* const* d_in, const int* in_sizes, int n_in,
                              void* d_out, int out_size, void* d_ws, size_t ws_size,
                              hipStream_t stream) {
  const float* hidden  = (const float*)d_in[0];
  const float* lengths = (const float*)d_in[1];
  const float* unoise  = (const float*)d_in[2];
  const float* W1  = (const float*)d_in[3];
  const float* b1  = (const float*)d_in[4];
  const float* W2  = (const float*)d_in[5];
  const float* b2  = (const float*)d_in[6];
  const float* Wq  = (const float*)d_in[7];
  const float* Wk  = (const float*)d_in[8];
  const float* simb   = (const float*)d_in[9];
  const float* lquery = (const float*)d_in[10];
  const float* Wpk = (const float*)d_in[11];
  const float* Wpv = (const float*)d_in[12];
  const float* Wpo = (const float*)d_in[13];
  const float* lng = (const float*)d_in[14];
  const float* lnb = (const float*)d_in[15];
  float* out = (float*)d_out;

  char* ws = (char*)d_ws;
  const size_t S = (size_t)Nz * Dz * 4;   // 12,288,000 B per slot
  float* U  = (float*)(ws);               // U -> KF
  float* HN = (float*)(ws + S);           // HN (persistent)
  float* C  = (float*)(ws + 2 * S);       // T1 -> QF -> POOLED
  float* Dv = (float*)(ws + 3 * S);       // M/V -> VALS
  char* tail = ws + 4 * S;
  float* probs  = (float*)tail; tail += 24064;   // B*L floats
  float* base   = (float*)tail; tail += 192000;  // B*L*NH floats
  int* segst    = (int*)tail;   tail += 24064;   // B*(L+1) ints
  int* segmeta  = (int*)tail;   tail += 256;     // B*2 ints
  float* wqe    = (float*)tail;                  // NH*D floats

  dim3 gg(4, (Nz + 127) / 128);   // M/128 x ceil(N/128)
  const size_t smem3 = 32768, smem1 = 16384;

  k_rowprep<<<Nz, 256, 0, stream>>>(hidden, lng, lnb, U, HN);
  gemm_mf<3><<<gg, 256, smem3, stream>>>(U, W1, b1, nullptr, C, Nz, 1);   // T1 = gelu(U@W1^T+b1)
  gemm_mf<3><<<gg, 256, smem3, stream>>>(C, W2, b2, U, Dv, Nz, 0);        // M = T1@W2^T+b2+U
  k_rownorm<<<Nz, 256, 0, stream>>>(Dv);                                  // V = l2norm(M)
  gemm_mf<3><<<gg, 256, smem3, stream>>>(Dv, Wq, nullptr, nullptr, C, Nz, 0);   // QF
  gemm_mf<3><<<gg, 256, smem3, stream>>>(Dv, Wk, nullptr, nullptr, U, Nz, 0);   // KF
  k_probs<<<dim3(Lz, Bz), 64, 0, stream>>>(C, U, simb, probs);
  k_boundary<<<Bz, 256, 0, stream>>>(probs, unoise, lengths, segst, segmeta);
  gemm_mf<1><<<gg, 256, smem1, stream>>>(HN, Wpv, nullptr, nullptr, Dv, Nz, 0); // VALS
  k_wqeff<<<NHz, 512, 0, stream>>>(lquery, Wpk, wqe);
  k_base<<<Nz, 256, 0, stream>>>(HN, wqe, base);
  k_pool<<<dim3(Lz, Bz), 256, 0, stream>>>(base, Dv, segst, segmeta, C);  // POOLED
  gemm_mf<1><<<gg, 256, smem1, stream>>>(C, Wpo, nullptr, nullptr, out, Nz, 0); // out = POOLED@Wpo^T
}

// Round 3
// 337.021 us; speedup vs baseline: 1.6374x; 1.5205x over previous
//
#include <hip/hip_runtime.h>
#include <math.h>

#define Bz 4
#define Lz 1500
#define Dz 512
#define NHz 8
#define Nz (Bz*Lz)       // 6000 rows
#define NRT 375          // 6000/16 row tiles
#define PEPSf 1.1920929e-07f

typedef __bf16 bf16x8 __attribute__((ext_vector_type(8)));
typedef unsigned short u16x8 __attribute__((ext_vector_type(8)));
typedef float f32x4 __attribute__((ext_vector_type(4)));

__device__ __forceinline__ unsigned short f2bf(float f) {
  unsigned u = __float_as_uint(f);
  return (unsigned short)((u + 0x7fffu + ((u >> 16) & 1u)) >> 16);
}
__device__ __forceinline__ float bf2f(unsigned short b) {
  return __uint_as_float(((unsigned)b) << 16);
}
// tiled bf16 plane layout: P[((row/16)*64 + col/8)*128 + (row%16)*8 + col%8]
__device__ __forceinline__ void st_tiled(unsigned short* __restrict__ P, int row, int col,
                                         unsigned short v) {
  P[(((row >> 4) * 64 + (col >> 3)) << 7) + ((row & 15) << 3) + (col & 7)] = v;
}

// ---------------- weights -> tiled bf16 hi/lo planes (once per launch) ----------------
__global__ __launch_bounds__(256) void k_wconv(
    const float* __restrict__ s0, const float* __restrict__ s1, const float* __restrict__ s2,
    const float* __restrict__ s3, const float* __restrict__ s4, const float* __restrict__ s5,
    unsigned short* __restrict__ h0, unsigned short* __restrict__ h1, unsigned short* __restrict__ h2,
    unsigned short* __restrict__ h3, unsigned short* __restrict__ h4, unsigned short* __restrict__ h5,
    unsigned short* __restrict__ l0, unsigned short* __restrict__ l1,
    unsigned short* __restrict__ l2, unsigned short* __restrict__ l3) {
  const int rt = blockIdx.x, mat = blockIdx.y, t = threadIdx.x;
  const float* S; unsigned short* H; unsigned short* L = nullptr;
  switch (mat) {
    case 0: S = s0; H = h0; L = l0; break;
    case 1: S = s1; H = h1; L = l1; break;
    case 2: S = s2; H = h2; L = l2; break;
    case 3: S = s3; H = h3; L = l3; break;
    case 4: S = s4; H = h4; break;
    default: S = s5; H = h5; break;
  }
  for (int e = t; e < 8192; e += 256) {
    int mm = e >> 9, c = e & 511;
    float x = S[(size_t)(rt * 16 + mm) * 512 + c];
    unsigned short hb = f2bf(x);
    int off = ((rt * 64 + (c >> 3)) << 7) + (mm << 3) + (c & 7);
    H[off] = hb;
    if (L) L[off] = f2bf(x - bf2f(hb));
  }
}

// ---------------- row prep: U = l2norm(hidden) (fp32 + hi/lo), HN = layernorm (fp32 + hi) ----
__global__ __launch_bounds__(256) void k_rowprep(const float* __restrict__ h,
    const float* __restrict__ g, const float* __restrict__ bb,
    float* __restrict__ U, float* __restrict__ HN,
    unsigned short* __restrict__ Uh, unsigned short* __restrict__ Ul,
    unsigned short* __restrict__ HNh) {
  const int row = blockIdx.x;
  const int t = threadIdx.x;
  const float* x = h + (size_t)row * Dz;
  float x0 = x[t], x1 = x[t + 256];
  float s = x0 + x1, q = x0 * x0 + x1 * x1;
  #pragma unroll
  for (int o = 32; o > 0; o >>= 1) { s += __shfl_xor(s, o, 64); q += __shfl_xor(q, o, 64); }
  __shared__ float ls[4], lq[4];
  if ((t & 63) == 0) { ls[t >> 6] = s; lq[t >> 6] = q; }
  __syncthreads();
  s = ls[0] + ls[1] + ls[2] + ls[3];
  q = lq[0] + lq[1] + lq[2] + lq[3];
  float un = 1.f / fmaxf(sqrtf(q), 1e-8f);
  float* up = U + (size_t)row * Dz;
  float u0 = x0 * un, u1 = x1 * un;
  up[t] = u0; up[t + 256] = u1;
  unsigned short hb0 = f2bf(u0), hb1 = f2bf(u1);
  st_tiled(Uh, row, t, hb0);       st_tiled(Ul, row, t, f2bf(u0 - bf2f(hb0)));
  st_tiled(Uh, row, t + 256, hb1); st_tiled(Ul, row, t + 256, f2bf(u1 - bf2f(hb1)));
  float mu = s * (1.f / 512.f);
  float var = fmaxf(q * (1.f / 512.f) - mu * mu, 0.f);
  float r = rsqrtf(var + 1e-5f);
  float* hp = HN + (size_t)row * Dz;
  float hn0 = (x0 - mu) * r * g[t] + bb[t];
  float hn1 = (x1 - mu) * r * g[t + 256] + bb[t + 256];
  hp[t] = hn0; hp[t + 256] = hn1;
  st_tiled(HNh, row, t, f2bf(hn0));
  st_tiled(HNh, row, t + 256, f2bf(hn1));
}

// ---------------- V = l2norm(M) -> tiled hi/lo planes ----------------
__global__ __launch_bounds__(256) void k_rownorm(const float* __restrict__ M,
    unsigned short* __restrict__ Vh, unsigned short* __restrict__ Vl) {
  const int row = blockIdx.x;
  const int t = threadIdx.x;
  const float* x = M + (size_t)row * Dz;
  float x0 = x[t], x1 = x[t + 256];
  float q = x0 * x0 + x1 * x1;
  #pragma unroll
  for (int o = 32; o > 0; o >>= 1) q += __shfl_xor(q, o, 64);
  __shared__ float lq[4];
  if ((t & 63) == 0) lq[t >> 6] = q;
  __syncthreads();
  q = lq[0] + lq[1] + lq[2] + lq[3];
  float un = 1.f / fmaxf(sqrtf(q), 1e-8f);
  float v0 = x0 * un, v1 = x1 * un;
  unsigned short hb0 = f2bf(v0), hb1 = f2bf(v1);
  st_tiled(Vh, row, t, hb0);       st_tiled(Vl, row, t, f2bf(v0 - bf2f(hb0)));
  st_tiled(Vh, row, t + 256, hb1); st_tiled(Vl, row, t + 256, f2bf(v1 - bf2f(hb1)));
}

// ---------------- direct-layout MFMA GEMM, no LDS, no barriers ----------------
// A: tiled bf16 planes [NRT'][64][16][8] ; B (weights): tiled [32][64][16][8].
// Block: 256 thr = 4 waves; tile 64 rows x 128 cols; wave w: cols w*32..+32.
// Each wave: 4 row-frags x 2 col-frags, K-loop 16 steps of 32.
template<int SPLIT>
__global__ __launch_bounds__(256, 2) void gemm_d(
    const unsigned short* __restrict__ Ah, const unsigned short* __restrict__ Al,
    const unsigned short* __restrict__ Bh, const unsigned short* __restrict__ Bl,
    const float* __restrict__ bias, const float* __restrict__ addsrc, int doGelu,
    float* __restrict__ outF, unsigned short* __restrict__ outH,
    unsigned short* __restrict__ outL) {
  const int t = threadIdx.x, w = t >> 6, l = t & 63;
  const int m = l & 15, q = l >> 4;
  const int rt0 = blockIdx.y * 4;
  const int ct0 = blockIdx.x * 8 + w * 2;
  const int laneoff = q * 128 + m * 8;

  const u16x8* pa[4]; const u16x8* pal[4];
  const u16x8* pb[2]; const u16x8* pbl[2];
  #pragma unroll
  for (int i = 0; i < 4; ++i) {
    int rt = min(rt0 + i, NRT - 1);       // clamp tail tile; stores are guarded
    pa[i] = (const u16x8*)(Ah + (size_t)rt * 8192 + laneoff);
    if (SPLIT == 3) pal[i] = (const u16x8*)(Al + (size_t)rt * 8192 + laneoff);
  }
  #pragma unroll
  for (int j = 0; j < 2; ++j) {
    pb[j] = (const u16x8*)(Bh + (size_t)(ct0 + j) * 8192 + laneoff);
    if (SPLIT == 3) pbl[j] = (const u16x8*)(Bl + (size_t)(ct0 + j) * 8192 + laneoff);
  }

  f32x4 acc[4][2];
  #pragma unroll
  for (int i = 0; i < 4; ++i)
    #pragma unroll
    for (int j = 0; j < 2; ++j) acc[i][j] = (f32x4){0.f, 0.f, 0.f, 0.f};

  #pragma unroll 4
  for (int s = 0; s < 16; ++s) {
    bf16x8 a[4], b[2];
    #pragma unroll
    for (int i = 0; i < 4; ++i) a[i] = __builtin_bit_cast(bf16x8, pa[i][s * 64]);
    #pragma unroll
    for (int j = 0; j < 2; ++j) b[j] = __builtin_bit_cast(bf16x8, pb[j][s * 64]);
    if (SPLIT == 3) {
      bf16x8 al_[4], bl_[2];
      #pragma unroll
      for (int i = 0; i < 4; ++i) al_[i] = __builtin_bit_cast(bf16x8, pal[i][s * 64]);
      #pragma unroll
      for (int j = 0; j < 2; ++j) bl_[j] = __builtin_bit_cast(bf16x8, pbl[j][s * 64]);
      #pragma unroll
      for (int i = 0; i < 4; ++i)
        #pragma unroll
        for (int j = 0; j < 2; ++j) {
          acc[i][j] = __builtin_amdgcn_mfma_f32_16x16x32_bf16(a[i], b[j], acc[i][j], 0, 0, 0);
          acc[i][j] = __builtin_amdgcn_mfma_f32_16x16x32_bf16(a[i], bl_[j], acc[i][j], 0, 0, 0);
          acc[i][j] = __builtin_amdgcn_mfma_f32_16x16x32_bf16(al_[i], b[j], acc[i][j], 0, 0, 0);
        }
    } else {
      #pragma unroll
      for (int i = 0; i < 4; ++i)
        #pragma unroll
        for (int j = 0; j < 2; ++j)
          acc[i][j] = __builtin_amdgcn_mfma_f32_16x16x32_bf16(a[i], b[j], acc[i][j], 0, 0, 0);
    }
  }

  // epilogue: C/D layout col = l&15 (=m), row = q*4 + r
  const int row0 = rt0 * 16;
  #pragma unroll
  for (int i = 0; i < 4; ++i) {
    #pragma unroll
    for (int r = 0; r < 4; ++r) {
      const int grow = row0 + i * 16 + q * 4 + r;
      if (grow >= Nz) continue;
      #pragma unroll
      for (int j = 0; j < 2; ++j) {
        const int gcol = (ct0 + j) * 16 + m;
        float v = acc[i][j][r];
        if (bias)   v += bias[gcol];
        if (addsrc) v += addsrc[(size_t)grow * Dz + gcol];
        if (doGelu) v = 0.5f * v * (1.f + erff(v * 0.70710678118654752f));
        if (outF) outF[(size_t)grow * Dz + gcol] = v;
        if (outH) {
          unsigned short hb = f2bf(v);
          st_tiled(outH, grow, gcol, hb);
          if (outL) st_tiled(outL, grow, gcol, f2bf(v - bf2f(hb)));
        }
      }
    }
  }
}

// ---------------- cos -> probs (padded). probs[b,L-1]=0 ----------------
__global__ void k_probs(const float* __restrict__ QF, const float* __restrict__ KF,
                        const float* __restrict__ simb, float* __restrict__ probs) {
  const int l = blockIdx.x, b = blockIdx.y, t = threadIdx.x;  // 64 threads
  if (l == Lz - 1) { if (t == 0) probs[(size_t)b * Lz + l] = 0.f; return; }
  const float* qp = QF + ((size_t)b * Lz + l) * Dz;
  const float* kp = KF + ((size_t)b * Lz + l + 1) * Dz;
  float acc = 0.f;
  for (int i = t; i < Dz; i += 64) acc += qp[i] * kp[i];
  #pragma unroll
  for (int o = 32; o > 0; o >>= 1) acc += __shfl_xor(acc, o, 64);
  if (t == 0) {
    float p = (1.f - (acc + simb[0])) * 0.5f;
    probs[(size_t)b * Lz + l] = fminf(fmaxf(p, 0.f), 1.f);
  }
}

// ---------------- boundaries, emergency, exclusive-scan segments ----------------
__global__ __launch_bounds__(256) void k_boundary(const float* __restrict__ probs,
    const float* __restrict__ un, const float* __restrict__ lengths,
    int* __restrict__ seg_start, int* __restrict__ seg_meta) {
  const int b = blockIdx.x, t = threadIdx.x;
  __shared__ float hard[Lz];
  __shared__ float ps[256];
  __shared__ float ws4[4];
  const float len = lengths[b];
  const int valid_len = min((int)(len * (Lz + 1)) - 1, Lz);
  const int Lm = (int)(len * Lz);
  const bool trunc = valid_len < Lz;
  for (int l = t; l < Lz; l += 256) {
    float p = probs[(size_t)b * Lz + l];
    p = fminf(fmaxf(p, PEPSf), 1.f - PEPSf);
    float u = un[(size_t)b * Lz + l];
    u = fminf(fmaxf(u, PEPSf), 1.f - PEPSf);
    float z = logf(p) - log1pf(-p) + logf(u) - log1pf(-u);
    float soft = 1.f / (1.f + expf(-z));
    float hd = soft > 0.5f ? 1.f : 0.f;
    if (trunc && l >= valid_len) hd = (l == valid_len) ? 1.f : 0.f;
    hard[l] = hd;
  }
  __syncthreads();
  float sm = 0.f;
  for (int l = t; l < Lz; l += 256) sm += hard[l];
  #pragma unroll
  for (int o = 32; o > 0; o >>= 1) sm += __shfl_xor(sm, o, 64);
  if ((t & 63) == 0) ws4[t >> 6] = sm;
  __syncthreads();
  float total = ws4[0] + ws4[1] + ws4[2] + ws4[3];
  if (total == 0.f && t == 0) hard[min(valid_len, Lz - 1)] = 1.f;
  __syncthreads();
  const int l0 = t * 6;
  float loc = 0.f;
  for (int i = 0; i < 6; ++i) { int l = l0 + i; if (l < Lz) loc += hard[l]; }
  ps[t] = loc;
  __syncthreads();
  for (int off = 1; off < 256; off <<= 1) {
    float v = (t >= off) ? ps[t - off] : 0.f;
    __syncthreads();
    ps[t] += v;
    __syncthreads();
  }
  float run = ps[t] - loc;
  for (int i = 0; i < 6; ++i) {
    int l = l0 + i; if (l >= Lz) break;
    int seg = (int)(run + 0.5f);
    if (l == 0) seg_start[b * (Lz + 1) + 0] = 0;
    else if (hard[l - 1] > 0.5f) seg_start[b * (Lz + 1) + seg] = l;
    if (l == Lz - 1) {
      int nseg = seg + 1;
      seg_meta[b * 2 + 0] = nseg;
      seg_meta[b * 2 + 1] = Lm;
      seg_start[b * (Lz + 1) + nseg] = Lz;
    }
    run += hard[l];
  }
}

// ---------------- wq_eff[h,d] = sum_e lq[h*64+e] * Wpk[h*64+e, d] ----------------
__global__ void k_wqeff(const float* __restrict__ lq, const float* __restrict__ Wpk,
                        float* __restrict__ wqe) {
  const int h = blockIdx.x, d = threadIdx.x;  // 512 threads
  float acc = 0.f;
  for (int e = 0; e < 64; ++e) acc += lq[h * 64 + e] * Wpk[(size_t)(h * 64 + e) * Dz + d];
  wqe[h * Dz + d] = acc;
}

// ---------------- base[row,h] = 0.125 * dot(HN[row], wq_eff[h]) ----------------
__global__ __launch_bounds__(256) void k_base(const float* __restrict__ HN,
    const float* __restrict__ wqe, float* __restrict__ base) {
  const int row = blockIdx.x, t = threadIdx.x;
  __shared__ float xs[Dz];
  xs[t] = HN[(size_t)row * Dz + t];
  xs[t + 256] = HN[(size_t)row * Dz + t + 256];
  __syncthreads();
  const int h = t >> 5, lane = t & 31;
  float acc = 0.f;
  for (int d = lane; d < Dz; d += 32) acc += xs[d] * wqe[h * Dz + d];
  #pragma unroll
  for (int o = 16; o > 0; o >>= 1) acc += __shfl_xor(acc, o, 32);
  if (lane == 0) base[(size_t)row * NHz + h] = acc * 0.125f;
}

// ---------------- segment softmax-pool over vals -> POOLED hi plane ----------------
__global__ __launch_bounds__(256) void k_pool(const float* __restrict__ base,
    const float* __restrict__ VALS, const int* __restrict__ seg_start,
    const int* __restrict__ seg_meta, unsigned short* __restrict__ Ph) {
  const int s = blockIdx.x, b = blockIdx.y, t = threadIdx.x;
  const int orow = b * Lz + s;
  const int nseg = seg_meta[b * 2], Lm = seg_meta[b * 2 + 1];
  int start = 0, end = 0;
  bool empty = true;
  if (s < nseg) {
    start = seg_start[b * (Lz + 1) + s];
    end = min(seg_start[b * (Lz + 1) + s + 1], Lm);
    empty = start >= end;
  }
  if (empty) { st_tiled(Ph, orow, t, 0); st_tiled(Ph, orow, t + 256, 0); return; }
  const int h = t >> 5, lane = t & 31;
  const float* bp = base + (size_t)b * Lz * NHz + h;
  float m = -1e30f;
  for (int l = start + lane; l < end; l += 32) m = fmaxf(m, bp[(size_t)l * NHz]);
  #pragma unroll
  for (int o = 16; o > 0; o >>= 1) m = fmaxf(m, __shfl_xor(m, o, 32));
  float den = 0.f;
  for (int l = start + lane; l < end; l += 32) den += expf(bp[(size_t)l * NHz] - m);
  #pragma unroll
  for (int o = 16; o > 0; o >>= 1) den += __shfl_xor(den, o, 32);
  float a0 = 0.f, a1 = 0.f;
  const float* vp = VALS + (size_t)b * Lz * Dz + h * 64 + lane;
  for (int l = start; l < end; ++l) {
    float wgt = expf(bp[(size_t)l * NHz] - m);
    a0 += wgt * vp[(size_t)l * Dz];
    a1 += wgt * vp[(size_t)l * Dz + 32];
  }
  float inv = 1.f / den;
  st_tiled(Ph, orow, h * 64 + lane, f2bf(a0 * inv));
  st_tiled(Ph, orow, h * 64 + lane + 32, f2bf(a1 * inv));
}

extern "C" void kernel_launch(void* const* d_in, const int* in_sizes, int n_in,
                              void* d_out, int out_size, void* d_ws, size_t ws_size,
                              hipStream_t stream) {
  const float* hidden  = (const float*)d_in[0];
  const float* lengths = (const float*)d_in[1];
  const float* unoise  = (const float*)d_in[2];
  const float* W1  = (const float*)d_in[3];
  const float* b1  = (const float*)d_in[4];
  const float* W2  = (const float*)d_in[5];
  const float* b2  = (const float*)d_in[6];
  const float* Wq  = (const float*)d_in[7];
  const float* Wk  = (const float*)d_in[8];
  const float* simb   = (const float*)d_in[9];
  const float* lquery = (const float*)d_in[10];
  const float* Wpk = (const float*)d_in[11];
  const float* Wpv = (const float*)d_in[12];
  const float* Wpo = (const float*)d_in[13];
  const float* lng = (const float*)d_in[14];
  const float* lnb = (const float*)d_in[15];
  float* out = (float*)d_out;

  char* p = (char*)d_ws;
  const size_t SF = (size_t)Nz * Dz * 4;          // fp32 slot: 12,288,000 B
  const size_t TP = (size_t)376 * 8192 * 2;       // tiled bf16 plane: 6,160,384 B
  const size_t WP = (size_t)32 * 8192 * 2;        // weight plane: 524,288 B
  float* U    = (float*)p; p += SF;
  float* HN   = (float*)p; p += SF;
  float* M    = (float*)p; p += SF;
  float* QF   = (float*)p; p += SF;
  float* KF   = (float*)p; p += SF;
  float* VALS = (float*)p; p += SF;
  unsigned short* Uh  = (unsigned short*)p; p += TP;
  unsigned short* Ul  = (unsigned short*)p; p += TP;
  unsigned short* T1h = (unsigned short*)p; p += TP;
  unsigned short* T1l = (unsigned short*)p; p += TP;
  unsigned short* Vh  = (unsigned short*)p; p += TP;
  unsigned short* Vl  = (unsigned short*)p; p += TP;
  unsigned short* HNh = (unsigned short*)p; p += TP;
  unsigned short* Ph  = (unsigned short*)p; p += TP;
  unsigned short* W1h = (unsigned short*)p; p += WP;
  unsigned short* W1l = (unsigned short*)p; p += WP;
  unsigned short* W2h = (unsigned short*)p; p += WP;
  unsigned short* W2l = (unsigned short*)p; p += WP;
  unsigned short* Wqh = (unsigned short*)p; p += WP;
  unsigned short* Wql = (unsigned short*)p; p += WP;
  unsigned short* Wkh = (unsigned short*)p; p += WP;
  unsigned short* Wkl = (unsigned short*)p; p += WP;
  unsigned short* Wpvh = (unsigned short*)p; p += WP;
  unsigned short* Wpoh = (unsigned short*)p; p += WP;
  float* probs  = (float*)p; p += 24064;
  float* base   = (float*)p; p += 192000;
  int* segst    = (int*)p;   p += 24064;
  int* segmeta  = (int*)p;   p += 256;
  float* wqe    = (float*)p;

  dim3 gg(4, 94);  // 128-col groups x 64-row tiles -> 376 blocks

  k_wconv<<<dim3(32, 6), 256, 0, stream>>>(W1, W2, Wq, Wk, Wpv, Wpo,
      W1h, W2h, Wqh, Wkh, Wpvh, Wpoh, W1l, W2l, Wql, Wkl);
  k_rowprep<<<Nz, 256, 0, stream>>>(hidden, lng, lnb, U, HN, Uh, Ul, HNh);
  gemm_d<3><<<gg, 256, 0, stream>>>(Uh, Ul, W1h, W1l, b1, nullptr, 1,
                                    nullptr, T1h, T1l);                 // T1 = gelu(U@W1^T+b1)
  gemm_d<3><<<gg, 256, 0, stream>>>(T1h, T1l, W2h, W2l, b2, U, 0,
                                    M, nullptr, nullptr);               // M = T1@W2^T+b2+U
  k_rownorm<<<Nz, 256, 0, stream>>>(M, Vh, Vl);                         // V = l2norm(M)
  gemm_d<3><<<gg, 256, 0, stream>>>(Vh, Vl, Wqh, Wql, nullptr, nullptr, 0,
                                    QF, nullptr, nullptr);              // QF = V@Wq^T
  gemm_d<3><<<gg, 256, 0, stream>>>(Vh, Vl, Wkh, Wkl, nullptr, nullptr, 0,
                                    KF, nullptr, nullptr);              // KF = V@Wk^T
  k_probs<<<dim3(Lz, Bz), 64, 0, stream>>>(QF, KF, simb, probs);
  k_boundary<<<Bz, 256, 0, stream>>>(probs, unoise, lengths, segst, segmeta);
  gemm_d<1><<<gg, 256, 0, stream>>>(HNh, nullptr, Wpvh, nullptr, nullptr, nullptr, 0,
                                    VALS, nullptr, nullptr);            // VALS = HN@Wpv^T
  k_wqeff<<<NHz, 512, 0, stream>>>(lquery, Wpk, wqe);
  k_base<<<Nz, 256, 0, stream>>>(HN, wqe, base);
  k_pool<<<dim3(Lz, Bz), 256, 0, stream>>>(base, VALS, segst, segmeta, Ph);  // POOLED (hi)
  gemm_d<1><<<gg, 256, 0, stream>>>(Ph, nullptr, Wpoh, nullptr, nullptr, nullptr, 0,
                                    out, nullptr, nullptr);             // out = POOLED@Wpo^T
}

// Round 5
// 262.001 us; speedup vs baseline: 2.1062x; 1.2863x over previous
//
#include <hip/hip_runtime.h>
#include <math.h>

#define Bz 4
#define Lz 1500
#define Dz 512
#define NHz 8
#define Nz (Bz*Lz)       // 6000 rows
#define NRT 375          // 6000/16 row tiles (exact)
#define PEPSf 1.1920929e-07f

typedef __bf16 bf16x8 __attribute__((ext_vector_type(8)));
typedef unsigned short u16x8 __attribute__((ext_vector_type(8)));
typedef float f32x4 __attribute__((ext_vector_type(4)));
typedef unsigned short us;

__device__ __forceinline__ us f2bf(float f) {
  unsigned u = __float_as_uint(f);
  return (us)((u + 0x7fffu + ((u >> 16) & 1u)) >> 16);
}
__device__ __forceinline__ float bf2f(us b) {
  return __uint_as_float(((unsigned)b) << 16);
}
// tiled bf16 plane: P[((row/16)*64 + col/8)*128 + (row%16)*8 + col%8]
__device__ __forceinline__ void st_tiled(us* __restrict__ P, int row, int col, us v) {
  P[(((row >> 4) * 64 + (col >> 3)) << 7) + ((row & 15) << 3) + (col & 7)] = v;
}

// XCD-swizzled block decode: same row-block's col-groups land on same XCD (%8 heuristic)
__device__ __forceinline__ bool decode_blk(int bx, int ncg, int& R, int& cg) {
  int xcd = bx & 7, v = bx >> 3;
  cg = v % ncg;
  R = (v / ncg) * 8 + xcd;
  return R < 94;
}

// ---------------- weights -> tiled bf16 hi/lo planes ----------------
__global__ __launch_bounds__(256) void k_wconv(
    const float* __restrict__ s0, const float* __restrict__ s1, const float* __restrict__ s2,
    const float* __restrict__ s3, const float* __restrict__ s4, const float* __restrict__ s5,
    us* __restrict__ h0, us* __restrict__ h1, us* __restrict__ h2,
    us* __restrict__ h3, us* __restrict__ h4, us* __restrict__ h5,
    us* __restrict__ l0, us* __restrict__ l1, us* __restrict__ l2, us* __restrict__ l3) {
  const int rt = blockIdx.x, mat = blockIdx.y, t = threadIdx.x;
  const float* S; us* H; us* L = nullptr;
  switch (mat) {
    case 0: S = s0; H = h0; L = l0; break;
    case 1: S = s1; H = h1; L = l1; break;
    case 2: S = s2; H = h2; L = l2; break;
    case 3: S = s3; H = h3; L = l3; break;
    case 4: S = s4; H = h4; break;
    default: S = s5; H = h5; break;
  }
  for (int e = t; e < 8192; e += 256) {
    int mm = e >> 9, c = e & 511;
    float x = S[(size_t)(rt * 16 + mm) * 512 + c];
    us hb = f2bf(x);
    int off = ((rt * 64 + (c >> 3)) << 7) + (mm << 3) + (c & 7);
    H[off] = hb;
    if (L) L[off] = f2bf(x - bf2f(hb));
  }
}

// ---------------- row prep: U = l2norm(h) (fp32+hi/lo); HN = layernorm (fp32+hi) ----------
__global__ __launch_bounds__(256) void k_rowprep(const float* __restrict__ h,
    const float* __restrict__ g, const float* __restrict__ bb,
    float* __restrict__ U, float* __restrict__ HN,
    us* __restrict__ Uh, us* __restrict__ Ul, us* __restrict__ HNh) {
  const int row = blockIdx.x;
  const int t = threadIdx.x;
  const float* x = h + (size_t)row * Dz;
  float x0 = x[t], x1 = x[t + 256];
  float s = x0 + x1, q = x0 * x0 + x1 * x1;
  #pragma unroll
  for (int o = 32; o > 0; o >>= 1) { s += __shfl_xor(s, o, 64); q += __shfl_xor(q, o, 64); }
  __shared__ float ls[4], lq[4];
  if ((t & 63) == 0) { ls[t >> 6] = s; lq[t >> 6] = q; }
  __syncthreads();
  s = ls[0] + ls[1] + ls[2] + ls[3];
  q = lq[0] + lq[1] + lq[2] + lq[3];
  float un = 1.f / fmaxf(sqrtf(q), 1e-8f);
  float u0 = x0 * un, u1 = x1 * un;
  float* up = U + (size_t)row * Dz;
  up[t] = u0; up[t + 256] = u1;
  us hb0 = f2bf(u0), hb1 = f2bf(u1);
  st_tiled(Uh, row, t, hb0);       st_tiled(Ul, row, t, f2bf(u0 - bf2f(hb0)));
  st_tiled(Uh, row, t + 256, hb1); st_tiled(Ul, row, t + 256, f2bf(u1 - bf2f(hb1)));
  float mu = s * (1.f / 512.f);
  float var = fmaxf(q * (1.f / 512.f) - mu * mu, 0.f);
  float r = rsqrtf(var + 1e-5f);
  float hn0 = (x0 - mu) * r * g[t] + bb[t];
  float hn1 = (x1 - mu) * r * g[t + 256] + bb[t + 256];
  float* hp = HN + (size_t)row * Dz;
  hp[t] = hn0; hp[t + 256] = hn1;
  st_tiled(HNh, row, t, f2bf(hn0));
  st_tiled(HNh, row, t + 256, f2bf(hn1));
}

// ---------------- V = l2norm(M) -> tiled hi/lo planes ----------------
__global__ __launch_bounds__(256) void k_rownorm(const float* __restrict__ M,
    us* __restrict__ Vh, us* __restrict__ Vl) {
  const int row = blockIdx.x;
  const int t = threadIdx.x;
  const float* x = M + (size_t)row * Dz;
  float x0 = x[t], x1 = x[t + 256];
  float q = x0 * x0 + x1 * x1;
  #pragma unroll
  for (int o = 32; o > 0; o >>= 1) q += __shfl_xor(q, o, 64);
  __shared__ float lq[4];
  if ((t & 63) == 0) lq[t >> 6] = q;
  __syncthreads();
  q = lq[0] + lq[1] + lq[2] + lq[3];
  float un = 1.f / fmaxf(sqrtf(q), 1e-8f);
  float v0 = x0 * un, v1 = x1 * un;
  us hb0 = f2bf(v0), hb1 = f2bf(v1);
  st_tiled(Vh, row, t, hb0);       st_tiled(Vl, row, t, f2bf(v0 - bf2f(hb0)));
  st_tiled(Vh, row, t + 256, hb1); st_tiled(Vl, row, t + 256, f2bf(v1 - bf2f(hb1)));
}

// ---------------- direct-layout MFMA GEMM body: no LDS, 1-deep register prefetch ----------
// Block: 4 waves; tile 64 rows (R*64) x 128 cols (cg*128); wave w: cols w*32..+32.
template<int SPLIT>
__device__ __forceinline__ void gemm_body(
    const us* __restrict__ Ah, const us* __restrict__ Al,
    const us* __restrict__ Bh, const us* __restrict__ Bl,
    const float* __restrict__ bias, const float* __restrict__ addsrc, int doGelu,
    float* __restrict__ outF, us* __restrict__ outH, us* __restrict__ outL,
    int R, int cg, int colbase) {
  const int t = threadIdx.x, w = t >> 6, l = t & 63;
  const int m = l & 15, q = l >> 4;
  const int rt0 = R * 4;
  const int ct0 = cg * 8 + w * 2;
  const int laneoff = q * 128 + m * 8;

  const u16x8* pa[4]; const u16x8* pal[4];
  const u16x8* pb[2]; const u16x8* pbl[2];
  #pragma unroll
  for (int i = 0; i < 4; ++i) {
    int rt = min(rt0 + i, NRT - 1);   // tail clamp; stores guarded
    pa[i] = (const u16x8*)(Ah + (size_t)rt * 8192 + laneoff);
    if (SPLIT == 3) pal[i] = (const u16x8*)(Al + (size_t)rt * 8192 + laneoff);
  }
  #pragma unroll
  for (int j = 0; j < 2; ++j) {
    pb[j] = (const u16x8*)(Bh + (size_t)(ct0 + j) * 8192 + laneoff);
    if (SPLIT == 3) pbl[j] = (const u16x8*)(Bl + (size_t)(ct0 + j) * 8192 + laneoff);
  }

  u16x8 bAh[2][4], bAl[2][4], bBh[2][2], bBl[2][2];
  #pragma unroll
  for (int i = 0; i < 4; ++i) {
    bAh[0][i] = pa[i][0];
    if (SPLIT == 3) bAl[0][i] = pal[i][0];
  }
  #pragma unroll
  for (int j = 0; j < 2; ++j) {
    bBh[0][j] = pb[j][0];
    if (SPLIT == 3) bBl[0][j] = pbl[j][0];
  }

  f32x4 acc[4][2];
  #pragma unroll
  for (int i = 0; i < 4; ++i)
    #pragma unroll
    for (int j = 0; j < 2; ++j) acc[i][j] = (f32x4){0.f, 0.f, 0.f, 0.f};

  #pragma unroll 2
  for (int s = 0; s < 16; ++s) {
    const int cur = s & 1, nxt = cur ^ 1;
    const int sn = (s + 1) & 15;      // wrap: final iter reloads step 0 (discarded)
    #pragma unroll
    for (int i = 0; i < 4; ++i) {
      bAh[nxt][i] = pa[i][sn * 64];
      if (SPLIT == 3) bAl[nxt][i] = pal[i][sn * 64];
    }
    #pragma unroll
    for (int j = 0; j < 2; ++j) {
      bBh[nxt][j] = pb[j][sn * 64];
      if (SPLIT == 3) bBl[nxt][j] = pbl[j][sn * 64];
    }
    #pragma unroll
    for (int i = 0; i < 4; ++i)
      #pragma unroll
      for (int j = 0; j < 2; ++j) {
        bf16x8 a = __builtin_bit_cast(bf16x8, bAh[cur][i]);
        bf16x8 b = __builtin_bit_cast(bf16x8, bBh[cur][j]);
        acc[i][j] = __builtin_amdgcn_mfma_f32_16x16x32_bf16(a, b, acc[i][j], 0, 0, 0);
        if (SPLIT == 3) {
          bf16x8 al_ = __builtin_bit_cast(bf16x8, bAl[cur][i]);
          bf16x8 bl_ = __builtin_bit_cast(bf16x8, bBl[cur][j]);
          acc[i][j] = __builtin_amdgcn_mfma_f32_16x16x32_bf16(a, bl_, acc[i][j], 0, 0, 0);
          acc[i][j] = __builtin_amdgcn_mfma_f32_16x16x32_bf16(al_, b, acc[i][j], 0, 0, 0);
        }
      }
  }

  // epilogue: C/D layout col = m, row = q*4 + r
  const int row0 = rt0 * 16;
  #pragma unroll
  for (int i = 0; i < 4; ++i) {
    #pragma unroll
    for (int r = 0; r < 4; ++r) {
      const int grow = row0 + i * 16 + q * 4 + r;
      if (grow >= Nz) continue;
      #pragma unroll
      for (int j = 0; j < 2; ++j) {
        const int gcol = colbase + (w * 2 + j) * 16 + m;
        float v = acc[i][j][r];
        if (bias)   v += bias[gcol];
        if (addsrc) v += addsrc[(size_t)grow * Dz + gcol];
        if (doGelu) v = 0.5f * v * (1.f + erff(v * 0.70710678118654752f));
        if (outF) outF[(size_t)grow * Dz + gcol] = v;
        if (outH) {
          us hb = f2bf(v);
          st_tiled(outH, grow, gcol, hb);
          if (outL) st_tiled(outL, grow, gcol, f2bf(v - bf2f(hb)));
        }
      }
    }
  }
}

// ---- wrapper kernels ----
__global__ __launch_bounds__(256, 2) void g_t1_vals(
    const us* Uh, const us* Ul, const us* W1h, const us* W1l, const float* b1, us* T1h, us* T1l,
    const us* HNh, const us* Wpvh, float* VALS) {
  int R, cg;
  if (!decode_blk(blockIdx.x, 4, R, cg)) return;
  if (blockIdx.z == 0)
    gemm_body<3>(Uh, Ul, W1h, W1l, b1, nullptr, 1, nullptr, T1h, T1l, R, cg, cg * 128);
  else
    gemm_body<1>(HNh, nullptr, Wpvh, nullptr, nullptr, nullptr, 0, VALS, nullptr, nullptr, R, cg, cg * 128);
}

__global__ __launch_bounds__(256, 2) void g_w2(
    const us* T1h, const us* T1l, const us* W2h, const us* W2l, const float* b2,
    const float* U, float* M) {
  int R, cg;
  if (!decode_blk(blockIdx.x, 4, R, cg)) return;
  gemm_body<3>(T1h, T1l, W2h, W2l, b2, U, 0, M, nullptr, nullptr, R, cg, cg * 128);
}

__global__ __launch_bounds__(256, 2) void g_qk(
    const us* Vh, const us* Vl, const us* Wqh, const us* Wql, const us* Wkh, const us* Wkl,
    float* QF, float* KF) {
  int R, cg;
  if (!decode_blk(blockIdx.x, 8, R, cg)) return;
  if (cg < 4)
    gemm_body<3>(Vh, Vl, Wqh, Wql, nullptr, nullptr, 0, QF, nullptr, nullptr, R, cg & 3, (cg & 3) * 128);
  else
    gemm_body<3>(Vh, Vl, Wkh, Wkl, nullptr, nullptr, 0, KF, nullptr, nullptr, R, cg & 3, (cg & 3) * 128);
}

__global__ __launch_bounds__(256, 2) void g_out(
    const us* Ph, const us* Wpoh, float* out) {
  int R, cg;
  if (!decode_blk(blockIdx.x, 4, R, cg)) return;
  gemm_body<1>(Ph, nullptr, Wpoh, nullptr, nullptr, nullptr, 0, out, nullptr, nullptr, R, cg, cg * 128);
}

// ---------------- cos -> probs ----------------
__global__ void k_probs(const float* __restrict__ QF, const float* __restrict__ KF,
                        const float* __restrict__ simb, float* __restrict__ probs) {
  const int l = blockIdx.x, b = blockIdx.y, t = threadIdx.x;  // 64 threads
  if (l == Lz - 1) { if (t == 0) probs[(size_t)b * Lz + l] = 0.f; return; }
  const float* qp = QF + ((size_t)b * Lz + l) * Dz;
  const float* kp = KF + ((size_t)b * Lz + l + 1) * Dz;
  float acc = 0.f;
  for (int i = t; i < Dz; i += 64) acc += qp[i] * kp[i];
  #pragma unroll
  for (int o = 32; o > 0; o >>= 1) acc += __shfl_xor(acc, o, 64);
  if (t == 0) {
    float p = (1.f - (acc + simb[0])) * 0.5f;
    probs[(size_t)b * Lz + l] = fminf(fmaxf(p, 0.f), 1.f);
  }
}

// ---------------- boundaries + scan ----------------
__global__ __launch_bounds__(256) void k_boundary(const float* __restrict__ probs,
    const float* __restrict__ un, const float* __restrict__ lengths,
    int* __restrict__ seg_start, int* __restrict__ seg_meta) {
  const int b = blockIdx.x, t = threadIdx.x;
  __shared__ float hard[Lz];
  __shared__ float ps[256];
  __shared__ float ws4[4];
  const float len = lengths[b];
  const int valid_len = min((int)(len * (Lz + 1)) - 1, Lz);
  const int Lm = (int)(len * Lz);
  const bool trunc = valid_len < Lz;
  for (int l = t; l < Lz; l += 256) {
    float p = probs[(size_t)b * Lz + l];
    p = fminf(fmaxf(p, PEPSf), 1.f - PEPSf);
    float u = un[(size_t)b * Lz + l];
    u = fminf(fmaxf(u, PEPSf), 1.f - PEPSf);
    float z = logf(p) - log1pf(-p) + logf(u) - log1pf(-u);
    float soft = 1.f / (1.f + expf(-z));
    float hd = soft > 0.5f ? 1.f : 0.f;
    if (trunc && l >= valid_len) hd = (l == valid_len) ? 1.f : 0.f;
    hard[l] = hd;
  }
  __syncthreads();
  float sm = 0.f;
  for (int l = t; l < Lz; l += 256) sm += hard[l];
  #pragma unroll
  for (int o = 32; o > 0; o >>= 1) sm += __shfl_xor(sm, o, 64);
  if ((t & 63) == 0) ws4[t >> 6] = sm;
  __syncthreads();
  float total = ws4[0] + ws4[1] + ws4[2] + ws4[3];
  if (total == 0.f && t == 0) hard[min(valid_len, Lz - 1)] = 1.f;
  __syncthreads();
  const int l0 = t * 6;
  float loc = 0.f;
  for (int i = 0; i < 6; ++i) { int l = l0 + i; if (l < Lz) loc += hard[l]; }
  ps[t] = loc;
  __syncthreads();
  for (int off = 1; off < 256; off <<= 1) {
    float v = (t >= off) ? ps[t - off] : 0.f;
    __syncthreads();
    ps[t] += v;
    __syncthreads();
  }
  float run = ps[t] - loc;
  for (int i = 0; i < 6; ++i) {
    int l = l0 + i; if (l >= Lz) break;
    int seg = (int)(run + 0.5f);
    if (l == 0) seg_start[b * (Lz + 1) + 0] = 0;
    else if (hard[l - 1] > 0.5f) seg_start[b * (Lz + 1) + seg] = l;
    if (l == Lz - 1) {
      int nseg = seg + 1;
      seg_meta[b * 2 + 0] = nseg;
      seg_meta[b * 2 + 1] = Lm;
      seg_start[b * (Lz + 1) + nseg] = Lz;
    }
    run += hard[l];
  }
}

// ---------------- wq_eff[h,d] = sum_e lq[h*64+e] * Wpk[h*64+e, d] ----------------
__global__ void k_wqeff(const float* __restrict__ lq, const float* __restrict__ Wpk,
                        float* __restrict__ wqe) {
  const int h = blockIdx.x, d = threadIdx.x;
  float acc = 0.f;
  for (int e = 0; e < 64; ++e) acc += lq[h * 64 + e] * Wpk[(size_t)(h * 64 + e) * Dz + d];
  wqe[h * Dz + d] = acc;
}

// ---------------- base[row,h] = 0.125 * dot(HN[row], wq_eff[h]) over ALL 512 dims ---------
__global__ __launch_bounds__(256) void k_base(const float* __restrict__ HN,
    const float* __restrict__ wqe, float* __restrict__ base) {
  const int row = blockIdx.x, t = threadIdx.x;
  __shared__ float xs[Dz];
  xs[t] = HN[(size_t)row * Dz + t];
  xs[t + 256] = HN[(size_t)row * Dz + t + 256];
  __syncthreads();
  const int h = t >> 5, lane = t & 31;
  float acc = 0.f;
  for (int d = lane; d < Dz; d += 32) acc += xs[d] * wqe[h * Dz + d];
  #pragma unroll
  for (int o = 16; o > 0; o >>= 1) acc += __shfl_xor(acc, o, 32);
  if (lane == 0) base[(size_t)row * NHz + h] = acc * 0.125f;
}

// ---------------- segment softmax-pool -> POOLED hi plane ----------------
__global__ __launch_bounds__(256) void k_pool(const float* __restrict__ base,
    const float* __restrict__ VALS, const int* __restrict__ seg_start,
    const int* __restrict__ seg_meta, us* __restrict__ Ph) {
  const int s = blockIdx.x, b = blockIdx.y, t = threadIdx.x;
  const int orow = b * Lz + s;
  const int nseg = seg_meta[b * 2], Lm = seg_meta[b * 2 + 1];
  int start = 0, end = 0;
  bool empty = true;
  if (s < nseg) {
    start = seg_start[b * (Lz + 1) + s];
    end = min(seg_start[b * (Lz + 1) + s + 1], Lm);
    empty = start >= end;
  }
  if (empty) { st_tiled(Ph, orow, t, 0); st_tiled(Ph, orow, t + 256, 0); return; }
  const int h = t >> 5, lane = t & 31;
  const float* bp = base + (size_t)b * Lz * NHz + h;
  float m = -1e30f;
  for (int l = start + lane; l < end; l += 32) m = fmaxf(m, bp[(size_t)l * NHz]);
  #pragma unroll
  for (int o = 16; o > 0; o >>= 1) m = fmaxf(m, __shfl_xor(m, o, 32));
  float den = 0.f;
  for (int l = start + lane; l < end; l += 32) den += expf(bp[(size_t)l * NHz] - m);
  #pragma unroll
  for (int o = 16; o > 0; o >>= 1) den += __shfl_xor(den, o, 32);
  float a0 = 0.f, a1 = 0.f;
  const float* vp = VALS + (size_t)b * Lz * Dz + h * 64 + lane;
  for (int l = start; l < end; ++l) {
    float wgt = expf(bp[(size_t)l * NHz] - m);
    a0 += wgt * vp[(size_t)l * Dz];
    a1 += wgt * vp[(size_t)l * Dz + 32];
  }
  float inv = 1.f / den;
  st_tiled(Ph, orow, h * 64 + lane, f2bf(a0 * inv));
  st_tiled(Ph, orow, h * 64 + lane + 32, f2bf(a1 * inv));
}

extern "C" void kernel_launch(void* const* d_in, const int* in_sizes, int n_in,
                              void* d_out, int out_size, void* d_ws, size_t ws_size,
                              hipStream_t stream) {
  const float* hidden  = (const float*)d_in[0];
  const float* lengths = (const float*)d_in[1];
  const float* unoise  = (const float*)d_in[2];
  const float* W1  = (const float*)d_in[3];
  const float* b1  = (const float*)d_in[4];
  const float* W2  = (const float*)d_in[5];
  const float* b2  = (const float*)d_in[6];
  const float* Wq  = (const float*)d_in[7];
  const float* Wk  = (const float*)d_in[8];
  const float* simb   = (const float*)d_in[9];
  const float* lquery = (const float*)d_in[10];
  const float* Wpk = (const float*)d_in[11];
  const float* Wpv = (const float*)d_in[12];
  const float* Wpo = (const float*)d_in[13];
  const float* lng = (const float*)d_in[14];
  const float* lnb = (const float*)d_in[15];
  float* out = (float*)d_out;

  char* p = (char*)d_ws;
  const size_t SF = (size_t)Nz * Dz * 4;          // 12,288,000 B
  const size_t TP = (size_t)376 * 8192 * 2;       // 6,160,384 B
  const size_t WP = (size_t)32 * 8192 * 2;        // 524,288 B
  float* U    = (float*)p; p += SF;
  float* HN   = (float*)p; p += SF;
  float* M    = (float*)p; p += SF;
  float* QF   = (float*)p; p += SF;
  float* KF   = (float*)p; p += SF;
  float* VALS = (float*)p; p += SF;
  us* Uh  = (us*)p; p += TP;
  us* Ul  = (us*)p; p += TP;
  us* T1h = (us*)p; p += TP;
  us* T1l = (us*)p; p += TP;
  us* Vh  = (us*)p; p += TP;
  us* Vl  = (us*)p; p += TP;
  us* HNh = (us*)p; p += TP;
  us* Ph  = (us*)p; p += TP;
  us* W1h = (us*)p; p += WP;
  us* W1l = (us*)p; p += WP;
  us* W2h = (us*)p; p += WP;
  us* W2l = (us*)p; p += WP;
  us* Wqh = (us*)p; p += WP;
  us* Wql = (us*)p; p += WP;
  us* Wkh = (us*)p; p += WP;
  us* Wkl = (us*)p; p += WP;
  us* Wpvh = (us*)p; p += WP;
  us* Wpoh = (us*)p; p += WP;
  float* probs  = (float*)p; p += 24064;
  float* base   = (float*)p; p += 192000;
  int* segst    = (int*)p;   p += 24064;
  int* segmeta  = (int*)p;   p += 256;
  float* wqe    = (float*)p;

  // swizzled 1-D grids: 8 XCD slots x 12 row groups x ncg col groups (R<94 filtered)
  const int G4 = 8 * 12 * 4;   // 384 (376 used)
  const int G8 = 8 * 12 * 8;   // 768 (752 used)

  k_wconv<<<dim3(32, 6), 256, 0, stream>>>(W1, W2, Wq, Wk, Wpv, Wpo,
      W1h, W2h, Wqh, Wkh, Wpvh, Wpoh, W1l, W2l, Wql, Wkl);
  k_wqeff<<<NHz, 512, 0, stream>>>(lquery, Wpk, wqe);
  k_rowprep<<<Nz, 256, 0, stream>>>(hidden, lng, lnb, U, HN, Uh, Ul, HNh);
  g_t1_vals<<<dim3(G4, 1, 2), 256, 0, stream>>>(Uh, Ul, W1h, W1l, b1, T1h, T1l,
                                                HNh, Wpvh, VALS);       // T1 & VALS
  g_w2<<<G4, 256, 0, stream>>>(T1h, T1l, W2h, W2l, b2, U, M);           // M = T1@W2^T+b2+U
  k_rownorm<<<Nz, 256, 0, stream>>>(M, Vh, Vl);                         // V = l2norm(M)
  g_qk<<<G8, 256, 0, stream>>>(Vh, Vl, Wqh, Wql, Wkh, Wkl, QF, KF);     // QF & KF
  k_probs<<<dim3(Lz, Bz), 64, 0, stream>>>(QF, KF, simb, probs);
  k_boundary<<<Bz, 256, 0, stream>>>(probs, unoise, lengths, segst, segmeta);
  k_base<<<Nz, 256, 0, stream>>>(HN, wqe, base);
  k_pool<<<dim3(Lz, Bz), 256, 0, stream>>>(base, VALS, segst, segmeta, Ph);
  g_out<<<G4, 256, 0, stream>>>(Ph, Wpoh, out);                         // out = POOLED@Wpo^T
}